// Round 6
// baseline (432.807 us; speedup 1.0000x reference)
//
#include <hip/hip_runtime.h>

typedef __attribute__((ext_vector_type(8))) short short8;
typedef __attribute__((ext_vector_type(4))) short s4v;
typedef __attribute__((ext_vector_type(4))) float floatx4;

#define CCH   256
#define QSCALE 0.17677669529663687f  // 32^-0.5

__device__ __forceinline__ unsigned short f2bf(float f) {
    unsigned u = __float_as_uint(f);
    u = u + 0x7fffu + ((u >> 16) & 1u);
    return (unsigned short)(u >> 16);
}

__device__ __forceinline__ void gl_lds16(const void* g, void* l) {
    __builtin_amdgcn_global_load_lds((const __attribute__((address_space(1))) void*)g,
                                     (__attribute__((address_space(3))) void*)l, 16, 0, 0);
}

// token (w*512+n) -> flat spatial offset (*CCH) in x/out with +4 cyclic shift
__device__ __forceinline__ int spatial_off(int token) {
    int w = token >> 9, n = token & 511;
    int wh = w >> 4, ww = (w >> 2) & 3, wd = w & 3;
    int h1 = n >> 6, w1 = (n >> 3) & 7, d1 = n & 7;
    int gh = (wh * 8 + h1 + 4) & 31;
    int gw = (ww * 8 + w1 + 4) & 31;
    int gd = (wd * 8 + d1 + 4) & 31;
    return ((gh * 32 + gw) * 32 + gd) * CCH;
}

// ---------------- x (fp32, spatial) -> Xw (bf16, window-token order) ----------------
__global__ __launch_bounds__(256) void xconv(const float* __restrict__ x,
                                             ushort* __restrict__ Xw) {
    int tid = blockIdx.x * 256 + threadIdx.x;   // 1048576
    int token = tid >> 5, c8 = (tid & 31) * 8;
    const float* src = x + spatial_off(token) + c8;
    float4 a = *(const float4*)src;
    float4 b = *(const float4*)(src + 4);
    ushort o[8] = {f2bf(a.x), f2bf(a.y), f2bf(a.z), f2bf(a.w),
                   f2bf(b.x), f2bf(b.y), f2bf(b.z), f2bf(b.w)};
    *(short8*)(Xw + (size_t)token * 256 + c8) = *(short8*)o;
}

// ---------------- weights fp32 -> bf16 (QSCALE folded into first 256 rows of Wq) ----
__global__ __launch_bounds__(256) void wconv(const float* __restrict__ Wq,
                                             const float* __restrict__ Wp,
                                             ushort* __restrict__ Wqb,
                                             ushort* __restrict__ Wpb) {
    int tid = blockIdx.x * 256 + threadIdx.x;   // 262144
    if (tid < 196608) {
        float s = (tid < 65536) ? QSCALE : 1.0f;
        Wqb[tid] = f2bf(Wq[tid] * s);
    } else {
        int i = tid - 196608;
        Wpb[i] = f2bf(Wp[i]);
    }
}

// -------- rel-pos pair table: Up[head*3375 + idx] = pack(bf(rpb[idx]), bf(rpb[idx-1])) ----
__global__ __launch_bounds__(256) void pair_prep(const float* __restrict__ rpb,
                                                 uint* __restrict__ Up) {
    int tid = blockIdx.x * 256 + threadIdx.x;   // 27000
    if (tid >= 27000) return;
    int head = tid / 3375, idx = tid - head * 3375;
    uint lo = f2bf(rpb[idx * 8 + head]);
    uint hi = f2bf(rpb[(idx > 0 ? idx - 1 : 0) * 8 + head]);
    Up[tid] = lo | (hi << 16);
}

// ---------------- MFMA GEMM: C[32768 x 768] = Xw @ Wqb^T -> Q/K/Vf ----------------
// V stored in K=16 MFMA A-fragment order per (w,head):
//   chunk = (n>>4)*2 + (hd>>4); elem = (((n>>2)&3)*16 + (hd&15))*4 + (n&3)
__global__ __launch_bounds__(256) void gemm_qkv(
    const ushort* __restrict__ A,   // [32768][256] bf16
    const ushort* __restrict__ Bw,  // [768][256] bf16
    const float* __restrict__ bq,
    ushort* __restrict__ Q, ushort* __restrict__ K, ushort* __restrict__ Vf) {
    __shared__ short As[128 * 64];
    __shared__ short Bs[128 * 64];
    const int t = threadIdx.x;
    const int wv = t >> 6, lane = t & 63, quad = lane >> 4, col = lane & 15;
    const int m0 = blockIdx.y * 128, n0 = blockIdx.x * 128;
    const int wm = (wv & 1) * 64, wn = (wv >> 1) * 64;

    floatx4 zf = {0.f, 0.f, 0.f, 0.f};
    floatx4 acc[4][4];
#pragma unroll
    for (int i = 0; i < 4; ++i)
#pragma unroll
        for (int j = 0; j < 4; ++j) acc[i][j] = zf;

    for (int kk = 0; kk < 256; kk += 64) {
        __syncthreads();
#pragma unroll
        for (int i = 0; i < 4; ++i) {
            int s = i * 256 + t;
            int row = s >> 3, qs = s & 7;
            int qg = qs ^ (row & 7);
            gl_lds16(A + (size_t)(m0 + row) * 256 + kk + qg * 8,
                     As + (i * 256 + wv * 64) * 8);
        }
#pragma unroll
        for (int i = 0; i < 4; ++i) {
            int s = i * 256 + t;
            int row = s >> 3, qs = s & 7;
            int qg = qs ^ (row & 7);
            gl_lds16(Bw + (size_t)(n0 + row) * 256 + kk + qg * 8,
                     Bs + (i * 256 + wv * 64) * 8);
        }
        __syncthreads();
#pragma unroll
        for (int h = 0; h < 2; ++h) {
            short8 af[4], bf[4];
#pragma unroll
            for (int mi = 0; mi < 4; ++mi) {
                int row = wm + mi * 16 + col;
                af[mi] = *(const short8*)(As + (row * 8 + ((h * 4 + quad) ^ (row & 7))) * 8);
            }
#pragma unroll
            for (int ni = 0; ni < 4; ++ni) {
                int row = wn + ni * 16 + col;
                bf[ni] = *(const short8*)(Bs + (row * 8 + ((h * 4 + quad) ^ (row & 7))) * 8);
            }
#pragma unroll
            for (int mi = 0; mi < 4; ++mi)
#pragma unroll
                for (int ni = 0; ni < 4; ++ni)
                    acc[mi][ni] = __builtin_amdgcn_mfma_f32_16x16x32_bf16(af[mi], bf[ni], acc[mi][ni], 0, 0, 0);
        }
    }

#pragma unroll
    for (int ni = 0; ni < 4; ++ni) {
        int j = n0 + wn + ni * 16 + col;
        int three = j >> 8, head = (j >> 5) & 7, hd = j & 31;
        float bias = bq[j] * ((j < 256) ? QSCALE : 1.0f);
        if (three == 2) {
            int h = hd >> 4, colv = hd & 15;
#pragma unroll
            for (int mi = 0; mi < 4; ++mi) {
#pragma unroll
                for (int r = 0; r < 4; ++r) {
                    int m = m0 + wm + mi * 16 + quad * 4 + r;
                    int w = m >> 9, n = m & 511;
                    size_t off = ((size_t)((w * 8 + head) * 64 + (n >> 4) * 2 + h) << 8)
                               + ((((n >> 2) & 3) * 16 + colv) << 2) + (n & 3);
                    Vf[off] = f2bf(acc[mi][ni][r] + bias);
                }
            }
        } else {
            ushort* dst = (three == 0) ? Q : K;
#pragma unroll
            for (int mi = 0; mi < 4; ++mi) {
#pragma unroll
                for (int r = 0; r < 4; ++r) {
                    int m = m0 + wm + mi * 16 + quad * 4 + r;
                    int w = m >> 9, n = m & 511;
                    dst[((size_t)(w * 8 + head) * 512 + n) * 32 + hd] = f2bf(acc[mi][ni][r] + bias);
                }
            }
        }
    }
}

// ---------------- MFMA GEMM: out = Y @ Wpb^T + bp, scatter w/ reverse shift ----------
__global__ __launch_bounds__(256) void gemm_proj(
    const ushort* __restrict__ A,   // Y [32768][256] bf16
    const ushort* __restrict__ Bw,  // [256][256] bf16
    const float* __restrict__ bp,
    float* __restrict__ out) {
    __shared__ short As[128 * 64];
    __shared__ short Bs[128 * 64];
    const int t = threadIdx.x;
    const int wv = t >> 6, lane = t & 63, quad = lane >> 4, col = lane & 15;
    const int m0 = blockIdx.y * 128, n0 = blockIdx.x * 128;
    const int wm = (wv & 1) * 64, wn = (wv >> 1) * 64;

    floatx4 zf = {0.f, 0.f, 0.f, 0.f};
    floatx4 acc[4][4];
#pragma unroll
    for (int i = 0; i < 4; ++i)
#pragma unroll
        for (int j = 0; j < 4; ++j) acc[i][j] = zf;

    for (int kk = 0; kk < 256; kk += 64) {
        __syncthreads();
#pragma unroll
        for (int i = 0; i < 4; ++i) {
            int s = i * 256 + t;
            int row = s >> 3, qs = s & 7;
            int qg = qs ^ (row & 7);
            gl_lds16(A + (size_t)(m0 + row) * 256 + kk + qg * 8,
                     As + (i * 256 + wv * 64) * 8);
        }
#pragma unroll
        for (int i = 0; i < 4; ++i) {
            int s = i * 256 + t;
            int row = s >> 3, qs = s & 7;
            int qg = qs ^ (row & 7);
            gl_lds16(Bw + (size_t)(n0 + row) * 256 + kk + qg * 8,
                     Bs + (i * 256 + wv * 64) * 8);
        }
        __syncthreads();
#pragma unroll
        for (int h = 0; h < 2; ++h) {
            short8 af[4], bf[4];
#pragma unroll
            for (int mi = 0; mi < 4; ++mi) {
                int row = wm + mi * 16 + col;
                af[mi] = *(const short8*)(As + (row * 8 + ((h * 4 + quad) ^ (row & 7))) * 8);
            }
#pragma unroll
            for (int ni = 0; ni < 4; ++ni) {
                int row = wn + ni * 16 + col;
                bf[ni] = *(const short8*)(Bs + (row * 8 + ((h * 4 + quad) ^ (row & 7))) * 8);
            }
#pragma unroll
            for (int mi = 0; mi < 4; ++mi)
#pragma unroll
                for (int ni = 0; ni < 4; ++ni)
                    acc[mi][ni] = __builtin_amdgcn_mfma_f32_16x16x32_bf16(af[mi], bf[ni], acc[mi][ni], 0, 0, 0);
        }
    }

#pragma unroll
    for (int ni = 0; ni < 4; ++ni) {
        int j = n0 + wn + ni * 16 + col;
        float bias = bp[j];
#pragma unroll
        for (int mi = 0; mi < 4; ++mi) {
#pragma unroll
            for (int r = 0; r < 4; ++r) {
                int m = m0 + wm + mi * 16 + quad * 4 + r;
                out[spatial_off(m) + j] = acc[mi][ni][r] + bias;
            }
        }
    }
}

// ---------------- MFMA windowed attention: S^T form, LDS pair-table bias ----------
__global__ __launch_bounds__(256, 2) void attn_kernel(
    const ushort* __restrict__ Q, const ushort* __restrict__ K,
    const ushort* __restrict__ Vf, const uint* __restrict__ Up,
    ushort* __restrict__ Y) {
    __shared__ short Kl[512 * 32];       // row-major [key][hd] bf16
    __shared__ short Vs[64 * 256];       // K=16 A-fragment order (pre-permuted in global)
    __shared__ uint  Ul[3375];           // per-head rel-pos pair table

    const int t = threadIdx.x;
    const int bid = blockIdx.x;
    const int w = bid >> 3, head = bid & 7;
    const int wh = w >> 4, ww = (w >> 2) & 3, wd = w & 3;
    const int wv = t >> 6, lane = t & 63, quad = lane >> 4, col = lane & 15;

    const ushort* Kg = K + (size_t)(w * 8 + head) * 512 * 32;
    const ushort* Vg = Vf + (size_t)(w * 8 + head) * 512 * 32;
    const ushort* Qg = Q + (size_t)(w * 8 + head) * 512 * 32;

    // ---- stage K and V once (async direct-to-LDS, linear) ----
#pragma unroll
    for (int i = 0; i < 8; ++i) {
        gl_lds16(Kg + (size_t)(i * 256 + t) * 8, Kl + (i * 256 + wv * 64) * 8);
        gl_lds16(Vg + (size_t)(i * 256 + t) * 8, Vs + (i * 256 + wv * 64) * 8);
    }
    // ---- stage this head's pair table ----
    const uint* Uph = Up + head * 3375;
    for (int i = t; i < 3375; i += 256) Ul[i] = Uph[i];

    // preload this wave's 8 Q B-fragments (overlaps staging latency)
    short8 qfs[8];
#pragma unroll
    for (int qs = 0; qs < 8; ++qs) {
        int qt = wv * 8 + qs;
        qfs[qs] = *(const short8*)(Qg + (size_t)(qt * 16 + col) * 32 + quad * 8);
    }
    __syncthreads();

    const bool boundary = (wh == 3) | (ww == 3) | (wd == 3);
    floatx4 zf = {0.f, 0.f, 0.f, 0.f};

    for (int qs = 0; qs < 8; ++qs) {
        const int qt = wv * 8 + qs;
        const short8 qf = qfs[qs];

        // ---- S^T = K Q^T : C-layout col=q(lane&15), row=key(quad*4+r), tile tt=key>>4
        floatx4 acc[32];
#pragma unroll
        for (int tt = 0; tt < 32; ++tt) {
            short8 kf = *(const short8*)(Kl + tt * 512 + col * 32 + quad * 8);
            acc[tt] = __builtin_amdgcn_mfma_f32_16x16x32_bf16(kf, qf, zf, 0, 0, 0);
        }

        // ---- rel-pos bias from LDS pair table ----
        // idx(r) = Base - Ktt - r;  Ul[i] = (lo=rpb[i], hi=rpb[i-1])
        const int qrow = qt * 16 + col;
        const int qh = qrow >> 6, qw = (qrow >> 3) & 7, qd = qrow & 7;
        const int Base = ((qh + 7) * 15 + (qw + 7 - (quad >> 1))) * 15
                       + (qd - ((quad & 1) << 2) + 7);
        const int cq = ((wh == 3) ? (1 + ((qrow >> 8) & 1)) * 16 : 0)
                     + ((ww == 3) ? (1 + ((qrow >> 5) & 1)) * 4 : 0)
                     + ((wd == 3) ? (1 + ((qrow >> 2) & 1)) : 0);
#pragma unroll
        for (int tt = 0; tt < 32; ++tt) {
            const int Ktt = ((tt >> 2) * 15 + (tt & 3) * 2) * 15;
            uint p0 = Ul[Base - Ktt];
            uint p1 = Ul[Base - Ktt - 2];
            acc[tt][0] += __uint_as_float(p0 << 16);
            acc[tt][1] += __uint_as_float(p0 & 0xffff0000u);
            acc[tt][2] += __uint_as_float(p1 << 16);
            acc[tt][3] += __uint_as_float(p1 & 0xffff0000u);
            if (boundary) {
                int key = tt * 16 + quad * 4;
                int ck = ((wh == 3) ? (1 + ((key >> 8) & 1)) * 16 : 0)
                       + ((ww == 3) ? (1 + ((key >> 5) & 1)) * 4 : 0)
                       + ((wd == 3) ? (1 + ((key >> 2) & 1)) : 0);
                float madd = (cq == ck) ? 0.f : -100.f;
#pragma unroll
                for (int r = 0; r < 4; ++r) acc[tt][r] += madd;
            }
        }

        // ---- softmax over keys: per-lane 128 vals + cross-quad reduction ----
        float m = acc[0][0];
#pragma unroll
        for (int tt = 0; tt < 32; ++tt) {
#pragma unroll
            for (int r = 0; r < 4; ++r) m = fmaxf(m, acc[tt][r]);
        }
        m = fmaxf(m, __shfl_xor(m, 16));
        m = fmaxf(m, __shfl_xor(m, 32));
        float rm = m * 1.442695041f;
        float rs = 0.f;
#pragma unroll
        for (int tt = 0; tt < 32; ++tt) {
#pragma unroll
            for (int r = 0; r < 4; ++r) {
                float e = exp2f(fmaf(acc[tt][r], 1.442695041f, -rm));
                acc[tt][r] = e;
                rs += e;
            }
        }
        rs += __shfl_xor(rs, 16);
        rs += __shfl_xor(rs, 32);
        float inv = 1.0f / rs;

        // ---- O^T = V^T P^T : P C-fragment IS the 16x16x16 B-operand, zero movement ----
        floatx4 o0 = zf, o1 = zf;
#pragma unroll
        for (int tt = 0; tt < 32; ++tt) {
            ushort pu[4] = {f2bf(acc[tt][0]), f2bf(acc[tt][1]), f2bf(acc[tt][2]), f2bf(acc[tt][3])};
            s4v pf = *(s4v*)pu;
            s4v v0 = *(const s4v*)(Vs + ((tt * 2 + 0) << 8) + lane * 4);
            s4v v1 = *(const s4v*)(Vs + ((tt * 2 + 1) << 8) + lane * 4);
            o0 = __builtin_amdgcn_mfma_f32_16x16x16bf16_1k(v0, pf, o0, 0, 0, 0);
            o1 = __builtin_amdgcn_mfma_f32_16x16x16bf16_1k(v1, pf, o1, 0, 0, 0);
        }

        // ---- epilogue: O^T row=hd(quad*4+r), col=q(lane&15); two 8B stores ----
        int token = w * 512 + qt * 16 + col;
        ushort* Yb = Y + (size_t)token * 256 + head * 32 + quad * 4;
        ushort4 s0, s1;
#pragma unroll
        for (int r = 0; r < 4; ++r) {
            ((ushort*)&s0)[r] = f2bf(o0[r] * inv);
            ((ushort*)&s1)[r] = f2bf(o1[r] * inv);
        }
        *(ushort4*)(Yb) = s0;
        *(ushort4*)(Yb + 16) = s1;
    }
}

extern "C" void kernel_launch(void* const* d_in, const int* in_sizes, int n_in,
                              void* d_out, int out_size, void* d_ws, size_t ws_size,
                              hipStream_t stream) {
    const float* x      = (const float*)d_in[0];
    const float* qkv_w  = (const float*)d_in[1];
    const float* qkv_b  = (const float*)d_in[2];
    const float* proj_w = (const float*)d_in[3];
    const float* proj_b = (const float*)d_in[4];
    const float* rpb    = (const float*)d_in[5];
    float* out = (float*)d_out;

    // ws layout (ushorts): Xw 8.39M | Q 8.39M | K 8.39M | Vf 8.39M | Y 8.39M | Up 54K | Wqb | Wpb
    ushort* Xw  = (ushort*)d_ws;
    ushort* Q   = Xw + 8388608;
    ushort* K   = Q + 8388608;
    ushort* Vf  = K + 8388608;
    ushort* Y   = Vf + 8388608;
    uint*   Up  = (uint*)(Y + 8388608);
    ushort* Wqb = (ushort*)(Up + 27008);
    ushort* Wpb = Wqb + 196608;

    xconv<<<dim3(4096), dim3(256), 0, stream>>>(x, Xw);
    wconv<<<dim3(1024), dim3(256), 0, stream>>>(qkv_w, proj_w, Wqb, Wpb);
    pair_prep<<<dim3(106), dim3(256), 0, stream>>>(rpb, Up);
    gemm_qkv<<<dim3(6, 256), dim3(256), 0, stream>>>(Xw, Wqb, qkv_b, Q, K, Vf);
    attn_kernel<<<dim3(512), dim3(256), 0, stream>>>(Q, K, Vf, Up, Y);
    gemm_proj<<<dim3(2, 256), dim3(256), 0, stream>>>(Y, Wpb, proj_b, out);
}

// Round 7
// 312.162 us; speedup vs baseline: 1.3865x; 1.3865x over previous
//
#include <hip/hip_runtime.h>

typedef __attribute__((ext_vector_type(8))) short short8;
typedef __attribute__((ext_vector_type(4))) short s4v;
typedef __attribute__((ext_vector_type(2))) uint uint2v;
typedef __attribute__((ext_vector_type(4))) float floatx4;

#define CCH   256
#define QSCALE 0.17677669529663687f  // 32^-0.5

__device__ __forceinline__ unsigned short f2bf(float f) {
    unsigned u = __float_as_uint(f);
    u = u + 0x7fffu + ((u >> 16) & 1u);
    return (unsigned short)(u >> 16);
}

__device__ __forceinline__ void gl_lds16(const void* g, void* l) {
    __builtin_amdgcn_global_load_lds((const __attribute__((address_space(1))) void*)g,
                                     (__attribute__((address_space(3))) void*)l, 16, 0, 0);
}

// token (w*512+n) -> flat spatial offset (*CCH) in x/out with +4 cyclic shift
__device__ __forceinline__ int spatial_off(int token) {
    int w = token >> 9, n = token & 511;
    int wh = w >> 4, ww = (w >> 2) & 3, wd = w & 3;
    int h1 = n >> 6, w1 = (n >> 3) & 7, d1 = n & 7;
    int gh = (wh * 8 + h1 + 4) & 31;
    int gw = (ww * 8 + w1 + 4) & 31;
    int gd = (wd * 8 + d1 + 4) & 31;
    return ((gh * 32 + gw) * 32 + gd) * CCH;
}

// ---------------- x (fp32, spatial) -> Xw (bf16, window-token order) ----------------
__global__ __launch_bounds__(256) void xconv(const float* __restrict__ x,
                                             ushort* __restrict__ Xw) {
    int tid = blockIdx.x * 256 + threadIdx.x;   // 1048576
    int token = tid >> 5, c8 = (tid & 31) * 8;
    const float* src = x + spatial_off(token) + c8;
    float4 a = *(const float4*)src;
    float4 b = *(const float4*)(src + 4);
    uint2v lo, hi;
    lo[0] = (uint)f2bf(a.x) | ((uint)f2bf(a.y) << 16);
    lo[1] = (uint)f2bf(a.z) | ((uint)f2bf(a.w) << 16);
    hi[0] = (uint)f2bf(b.x) | ((uint)f2bf(b.y) << 16);
    hi[1] = (uint)f2bf(b.z) | ((uint)f2bf(b.w) << 16);
    uint2v* dst = (uint2v*)(Xw + (size_t)token * 256 + c8);
    dst[0] = lo;
    dst[1] = hi;
}

// ---------------- weights fp32 -> bf16 (QSCALE folded into first 256 rows of Wq) ----
__global__ __launch_bounds__(256) void wconv(const float* __restrict__ Wq,
                                             const float* __restrict__ Wp,
                                             ushort* __restrict__ Wqb,
                                             ushort* __restrict__ Wpb) {
    int tid = blockIdx.x * 256 + threadIdx.x;   // 262144
    if (tid < 196608) {
        float s = (tid < 65536) ? QSCALE : 1.0f;
        Wqb[tid] = f2bf(Wq[tid] * s);
    } else {
        int i = tid - 196608;
        Wpb[i] = f2bf(Wp[i]);
    }
}

// -------- rel-pos pair table: Up[head*3375 + idx] = pack(bf(rpb[idx]), bf(rpb[idx-1])) ----
__global__ __launch_bounds__(256) void pair_prep(const float* __restrict__ rpb,
                                                 uint* __restrict__ Up) {
    int tid = blockIdx.x * 256 + threadIdx.x;   // 27000
    if (tid >= 27000) return;
    int head = tid / 3375, idx = tid - head * 3375;
    uint lo = f2bf(rpb[idx * 8 + head]);
    uint hi = f2bf(rpb[(idx > 0 ? idx - 1 : 0) * 8 + head]);
    Up[tid] = lo | (hi << 16);
}

// ---------------- MFMA GEMM: C[32768 x 768] = Xw @ Wqb^T -> Q/K/Vf ----------------
// V stored in K=16 MFMA A-fragment order per (w,head):
//   chunk = (n>>4)*2 + (hd>>4); elem = (((n>>2)&3)*16 + (hd&15))*4 + (n&3)
__global__ __launch_bounds__(256) void gemm_qkv(
    const ushort* __restrict__ A,   // [32768][256] bf16
    const ushort* __restrict__ Bw,  // [768][256] bf16
    const float* __restrict__ bq,
    ushort* __restrict__ Q, ushort* __restrict__ K, ushort* __restrict__ Vf) {
    __shared__ short As[128 * 64];
    __shared__ short Bs[128 * 64];
    const int t = threadIdx.x;
    const int wv = t >> 6, lane = t & 63, quad = lane >> 4, col = lane & 15;
    const int m0 = blockIdx.y * 128, n0 = blockIdx.x * 128;
    const int wm = (wv & 1) * 64, wn = (wv >> 1) * 64;

    floatx4 zf = {0.f, 0.f, 0.f, 0.f};
    floatx4 acc[4][4];
#pragma unroll
    for (int i = 0; i < 4; ++i)
#pragma unroll
        for (int j = 0; j < 4; ++j) acc[i][j] = zf;

    for (int kk = 0; kk < 256; kk += 64) {
        __syncthreads();
#pragma unroll
        for (int i = 0; i < 4; ++i) {
            int s = i * 256 + t;
            int row = s >> 3, qs = s & 7;
            int qg = qs ^ (row & 7);
            gl_lds16(A + (size_t)(m0 + row) * 256 + kk + qg * 8,
                     As + (i * 256 + wv * 64) * 8);
        }
#pragma unroll
        for (int i = 0; i < 4; ++i) {
            int s = i * 256 + t;
            int row = s >> 3, qs = s & 7;
            int qg = qs ^ (row & 7);
            gl_lds16(Bw + (size_t)(n0 + row) * 256 + kk + qg * 8,
                     Bs + (i * 256 + wv * 64) * 8);
        }
        __syncthreads();
#pragma unroll
        for (int h = 0; h < 2; ++h) {
            short8 af[4], bf[4];
#pragma unroll
            for (int mi = 0; mi < 4; ++mi) {
                int row = wm + mi * 16 + col;
                af[mi] = *(const short8*)(As + (row * 8 + ((h * 4 + quad) ^ (row & 7))) * 8);
            }
#pragma unroll
            for (int ni = 0; ni < 4; ++ni) {
                int row = wn + ni * 16 + col;
                bf[ni] = *(const short8*)(Bs + (row * 8 + ((h * 4 + quad) ^ (row & 7))) * 8);
            }
#pragma unroll
            for (int mi = 0; mi < 4; ++mi)
#pragma unroll
                for (int ni = 0; ni < 4; ++ni)
                    acc[mi][ni] = __builtin_amdgcn_mfma_f32_16x16x32_bf16(af[mi], bf[ni], acc[mi][ni], 0, 0, 0);
        }
    }

#pragma unroll
    for (int ni = 0; ni < 4; ++ni) {
        int j = n0 + wn + ni * 16 + col;
        int three = j >> 8, head = (j >> 5) & 7, hd = j & 31;
        float bias = bq[j] * ((j < 256) ? QSCALE : 1.0f);
        if (three == 2) {
            int h = hd >> 4, colv = hd & 15;
#pragma unroll
            for (int mi = 0; mi < 4; ++mi) {
#pragma unroll
                for (int r = 0; r < 4; ++r) {
                    int m = m0 + wm + mi * 16 + quad * 4 + r;
                    int w = m >> 9, n = m & 511;
                    size_t off = ((size_t)((w * 8 + head) * 64 + (n >> 4) * 2 + h) << 8)
                               + ((((n >> 2) & 3) * 16 + colv) << 2) + (n & 3);
                    Vf[off] = f2bf(acc[mi][ni][r] + bias);
                }
            }
        } else {
            ushort* dst = (three == 0) ? Q : K;
#pragma unroll
            for (int mi = 0; mi < 4; ++mi) {
#pragma unroll
                for (int r = 0; r < 4; ++r) {
                    int m = m0 + wm + mi * 16 + quad * 4 + r;
                    int w = m >> 9, n = m & 511;
                    dst[((size_t)(w * 8 + head) * 512 + n) * 32 + hd] = f2bf(acc[mi][ni][r] + bias);
                }
            }
        }
    }
}

// ---------------- MFMA GEMM: out = Y @ Wpb^T + bp, scatter w/ reverse shift ----------
__global__ __launch_bounds__(256) void gemm_proj(
    const ushort* __restrict__ A,   // Y [32768][256] bf16
    const ushort* __restrict__ Bw,  // [256][256] bf16
    const float* __restrict__ bp,
    float* __restrict__ out) {
    __shared__ short As[128 * 64];
    __shared__ short Bs[128 * 64];
    const int t = threadIdx.x;
    const int wv = t >> 6, lane = t & 63, quad = lane >> 4, col = lane & 15;
    const int m0 = blockIdx.y * 128, n0 = blockIdx.x * 128;
    const int wm = (wv & 1) * 64, wn = (wv >> 1) * 64;

    floatx4 zf = {0.f, 0.f, 0.f, 0.f};
    floatx4 acc[4][4];
#pragma unroll
    for (int i = 0; i < 4; ++i)
#pragma unroll
        for (int j = 0; j < 4; ++j) acc[i][j] = zf;

    for (int kk = 0; kk < 256; kk += 64) {
        __syncthreads();
#pragma unroll
        for (int i = 0; i < 4; ++i) {
            int s = i * 256 + t;
            int row = s >> 3, qs = s & 7;
            int qg = qs ^ (row & 7);
            gl_lds16(A + (size_t)(m0 + row) * 256 + kk + qg * 8,
                     As + (i * 256 + wv * 64) * 8);
        }
#pragma unroll
        for (int i = 0; i < 4; ++i) {
            int s = i * 256 + t;
            int row = s >> 3, qs = s & 7;
            int qg = qs ^ (row & 7);
            gl_lds16(Bw + (size_t)(n0 + row) * 256 + kk + qg * 8,
                     Bs + (i * 256 + wv * 64) * 8);
        }
        __syncthreads();
#pragma unroll
        for (int h = 0; h < 2; ++h) {
            short8 af[4], bf[4];
#pragma unroll
            for (int mi = 0; mi < 4; ++mi) {
                int row = wm + mi * 16 + col;
                af[mi] = *(const short8*)(As + (row * 8 + ((h * 4 + quad) ^ (row & 7))) * 8);
            }
#pragma unroll
            for (int ni = 0; ni < 4; ++ni) {
                int row = wn + ni * 16 + col;
                bf[ni] = *(const short8*)(Bs + (row * 8 + ((h * 4 + quad) ^ (row & 7))) * 8);
            }
#pragma unroll
            for (int mi = 0; mi < 4; ++mi)
#pragma unroll
                for (int ni = 0; ni < 4; ++ni)
                    acc[mi][ni] = __builtin_amdgcn_mfma_f32_16x16x32_bf16(af[mi], bf[ni], acc[mi][ni], 0, 0, 0);
        }
    }

#pragma unroll
    for (int ni = 0; ni < 4; ++ni) {
        int j = n0 + wn + ni * 16 + col;
        float bias = bp[j];
#pragma unroll
        for (int mi = 0; mi < 4; ++mi) {
#pragma unroll
            for (int r = 0; r < 4; ++r) {
                int m = m0 + wm + mi * 16 + quad * 4 + r;
                out[spatial_off(m) + j] = acc[mi][ni][r] + bias;
            }
        }
    }
}

// ---------------- MFMA windowed attention: S^T form, scratch-free register paths ----
__global__ __launch_bounds__(256, 2) void attn_kernel(
    const ushort* __restrict__ Q, const ushort* __restrict__ K,
    const ushort* __restrict__ Vf, const uint* __restrict__ Up,
    ushort* __restrict__ Y) {
    __shared__ short Kl[512 * 32];       // row-major [key][hd] bf16
    __shared__ short Vs[64 * 256];       // K=16 A-fragment order (pre-permuted in global)
    __shared__ uint  Ul[3375];           // per-head rel-pos pair table

    const int t = threadIdx.x;
    const int bid = blockIdx.x;
    const int w = bid >> 3, head = bid & 7;
    const int wh = w >> 4, ww = (w >> 2) & 3, wd = w & 3;
    const int wv = t >> 6, lane = t & 63, quad = lane >> 4, col = lane & 15;

    const ushort* Kg = K + (size_t)(w * 8 + head) * 512 * 32;
    const ushort* Vg = Vf + (size_t)(w * 8 + head) * 512 * 32;
    const ushort* Qg = Q + (size_t)(w * 8 + head) * 512 * 32;

    // ---- stage K and V once (async direct-to-LDS, linear) ----
#pragma unroll
    for (int i = 0; i < 8; ++i) {
        gl_lds16(Kg + (size_t)(i * 256 + t) * 8, Kl + (i * 256 + wv * 64) * 8);
        gl_lds16(Vg + (size_t)(i * 256 + t) * 8, Vs + (i * 256 + wv * 64) * 8);
    }
    // ---- stage this head's pair table ----
    const uint* Uph = Up + head * 3375;
    for (int i = t; i < 3375; i += 256) Ul[i] = Uph[i];
    __syncthreads();

    const bool boundary = (wh == 3) | (ww == 3) | (wd == 3);
    floatx4 zf = {0.f, 0.f, 0.f, 0.f};

    for (int qs = 0; qs < 8; ++qs) {
        const int qt = wv * 8 + qs;
        const short8 qf = *(const short8*)(Qg + (size_t)(qt * 16 + col) * 32 + quad * 8);

        // ---- S^T = K Q^T : C-layout col=q(lane&15), row=key(quad*4+r), tile tt=key>>4
        floatx4 acc[32];
#pragma unroll
        for (int tt = 0; tt < 32; ++tt) {
            short8 kf = *(const short8*)(Kl + tt * 512 + col * 32 + quad * 8);
            acc[tt] = __builtin_amdgcn_mfma_f32_16x16x32_bf16(kf, qf, zf, 0, 0, 0);
        }

        // ---- rel-pos bias from LDS pair table: idx(r) = Base - Ktt - r ----
        const int qrow = qt * 16 + col;
        const int qh = qrow >> 6, qw = (qrow >> 3) & 7, qd = qrow & 7;
        const int Base = ((qh + 7) * 15 + (qw + 7 - (quad >> 1))) * 15
                       + (qd - ((quad & 1) << 2) + 7);
        const int cq = ((wh == 3) ? (1 + ((qrow >> 8) & 1)) * 16 : 0)
                     + ((ww == 3) ? (1 + ((qrow >> 5) & 1)) * 4 : 0)
                     + ((wd == 3) ? (1 + ((qrow >> 2) & 1)) : 0);
#pragma unroll
        for (int tt = 0; tt < 32; ++tt) {
            const int Ktt = ((tt >> 2) * 15 + (tt & 3) * 2) * 15;
            uint p0 = Ul[Base - Ktt];
            uint p1 = Ul[Base - Ktt - 2];
            acc[tt][0] += __uint_as_float(p0 << 16);
            acc[tt][1] += __uint_as_float(p0 & 0xffff0000u);
            acc[tt][2] += __uint_as_float(p1 << 16);
            acc[tt][3] += __uint_as_float(p1 & 0xffff0000u);
            if (boundary) {
                int key = tt * 16 + quad * 4;
                int ck = ((wh == 3) ? (1 + ((key >> 8) & 1)) * 16 : 0)
                       + ((ww == 3) ? (1 + ((key >> 5) & 1)) * 4 : 0)
                       + ((wd == 3) ? (1 + ((key >> 2) & 1)) : 0);
                float madd = (cq == ck) ? 0.f : -100.f;
#pragma unroll
                for (int r = 0; r < 4; ++r) acc[tt][r] += madd;
            }
        }

        // ---- row max over this lane's 128 keys + cross-quad reduction ----
        float m = acc[0][0];
#pragma unroll
        for (int tt = 0; tt < 32; ++tt) {
#pragma unroll
            for (int r = 0; r < 4; ++r) m = fmaxf(m, acc[tt][r]);
        }
        m = fmaxf(m, __shfl_xor(m, 16));
        m = fmaxf(m, __shfl_xor(m, 32));
        const float rm = m * 1.442695041f;

        // ---- merged exp + pack + PV (single consume pass over acc) ----
        float rs = 0.f;
        floatx4 o0 = zf, o1 = zf;
#pragma unroll
        for (int tt = 0; tt < 32; ++tt) {
            float e0 = exp2f(fmaf(acc[tt][0], 1.442695041f, -rm));
            float e1 = exp2f(fmaf(acc[tt][1], 1.442695041f, -rm));
            float e2 = exp2f(fmaf(acc[tt][2], 1.442695041f, -rm));
            float e3 = exp2f(fmaf(acc[tt][3], 1.442695041f, -rm));
            rs += (e0 + e1) + (e2 + e3);
            uint2v pp;
            pp[0] = (uint)f2bf(e0) | ((uint)f2bf(e1) << 16);
            pp[1] = (uint)f2bf(e2) | ((uint)f2bf(e3) << 16);
            s4v pf = __builtin_bit_cast(s4v, pp);
            s4v v0 = *(const s4v*)(Vs + ((tt * 2 + 0) << 8) + lane * 4);
            s4v v1 = *(const s4v*)(Vs + ((tt * 2 + 1) << 8) + lane * 4);
            o0 = __builtin_amdgcn_mfma_f32_16x16x16bf16_1k(v0, pf, o0, 0, 0, 0);
            o1 = __builtin_amdgcn_mfma_f32_16x16x16bf16_1k(v1, pf, o1, 0, 0, 0);
        }
        rs += __shfl_xor(rs, 16);
        rs += __shfl_xor(rs, 32);
        const float inv = 1.0f / rs;

        // ---- epilogue: O^T row=hd(quad*4+r), col=q(lane&15); two packed 8B stores ----
        int token = w * 512 + qt * 16 + col;
        ushort* Yb = Y + (size_t)token * 256 + head * 32 + quad * 4;
        uint2v y0, y1;
        y0[0] = (uint)f2bf(o0[0] * inv) | ((uint)f2bf(o0[1] * inv) << 16);
        y0[1] = (uint)f2bf(o0[2] * inv) | ((uint)f2bf(o0[3] * inv) << 16);
        y1[0] = (uint)f2bf(o1[0] * inv) | ((uint)f2bf(o1[1] * inv) << 16);
        y1[1] = (uint)f2bf(o1[2] * inv) | ((uint)f2bf(o1[3] * inv) << 16);
        *(uint2v*)(Yb) = y0;
        *(uint2v*)(Yb + 16) = y1;
    }
}

extern "C" void kernel_launch(void* const* d_in, const int* in_sizes, int n_in,
                              void* d_out, int out_size, void* d_ws, size_t ws_size,
                              hipStream_t stream) {
    const float* x      = (const float*)d_in[0];
    const float* qkv_w  = (const float*)d_in[1];
    const float* qkv_b  = (const float*)d_in[2];
    const float* proj_w = (const float*)d_in[3];
    const float* proj_b = (const float*)d_in[4];
    const float* rpb    = (const float*)d_in[5];
    float* out = (float*)d_out;

    // ws layout (ushorts): Xw 8.39M | Q 8.39M | K 8.39M | Vf 8.39M | Y 8.39M | Up 54K | Wqb | Wpb
    ushort* Xw  = (ushort*)d_ws;
    ushort* Q   = Xw + 8388608;
    ushort* K   = Q + 8388608;
    ushort* Vf  = K + 8388608;
    ushort* Y   = Vf + 8388608;
    uint*   Up  = (uint*)(Y + 8388608);
    ushort* Wqb = (ushort*)(Up + 27008);
    ushort* Wpb = Wqb + 196608;

    xconv<<<dim3(4096), dim3(256), 0, stream>>>(x, Xw);
    wconv<<<dim3(1024), dim3(256), 0, stream>>>(qkv_w, proj_w, Wqb, Wpb);
    pair_prep<<<dim3(106), dim3(256), 0, stream>>>(rpb, Up);
    gemm_qkv<<<dim3(6, 256), dim3(256), 0, stream>>>(Xw, Wqb, qkv_b, Q, K, Vf);
    attn_kernel<<<dim3(512), dim3(256), 0, stream>>>(Q, K, Vf, Up, Y);
    gemm_proj<<<dim3(2, 256), dim3(256), 0, stream>>>(Y, Wpb, proj_b, out);
}

// Round 8
// 209.732 us; speedup vs baseline: 2.0636x; 1.4884x over previous
//
#include <hip/hip_runtime.h>

typedef __attribute__((ext_vector_type(8))) short short8;
typedef __attribute__((ext_vector_type(4))) short s4v;
typedef __attribute__((ext_vector_type(2))) uint uint2v;
typedef __attribute__((ext_vector_type(4))) float floatx4;

#define CCH   256
#define QSCALE 0.17677669529663687f  // 32^-0.5

__device__ __forceinline__ unsigned short f2bf(float f) {
    unsigned u = __float_as_uint(f);
    u = u + 0x7fffu + ((u >> 16) & 1u);
    return (unsigned short)(u >> 16);
}

__device__ __forceinline__ void gl_lds16(const void* g, void* l) {
    __builtin_amdgcn_global_load_lds((const __attribute__((address_space(1))) void*)g,
                                     (__attribute__((address_space(3))) void*)l, 16, 0, 0);
}

// token (w*512+n) -> flat spatial offset (*CCH) in x/out with +4 cyclic shift
__device__ __forceinline__ int spatial_off(int token) {
    int w = token >> 9, n = token & 511;
    int wh = w >> 4, ww = (w >> 2) & 3, wd = w & 3;
    int h1 = n >> 6, w1 = (n >> 3) & 7, d1 = n & 7;
    int gh = (wh * 8 + h1 + 4) & 31;
    int gw = (ww * 8 + w1 + 4) & 31;
    int gd = (wd * 8 + d1 + 4) & 31;
    return ((gh * 32 + gw) * 32 + gd) * CCH;
}

// ---------------- x (fp32, spatial) -> Xw (bf16, window-token order) ----------------
__global__ __launch_bounds__(256) void xconv(const float* __restrict__ x,
                                             ushort* __restrict__ Xw) {
    int tid = blockIdx.x * 256 + threadIdx.x;   // 1048576
    int token = tid >> 5, c8 = (tid & 31) * 8;
    const float* src = x + spatial_off(token) + c8;
    float4 a = *(const float4*)src;
    float4 b = *(const float4*)(src + 4);
    uint2v lo, hi;
    lo[0] = (uint)f2bf(a.x) | ((uint)f2bf(a.y) << 16);
    lo[1] = (uint)f2bf(a.z) | ((uint)f2bf(a.w) << 16);
    hi[0] = (uint)f2bf(b.x) | ((uint)f2bf(b.y) << 16);
    hi[1] = (uint)f2bf(b.z) | ((uint)f2bf(b.w) << 16);
    uint2v* dst = (uint2v*)(Xw + (size_t)token * 256 + c8);
    dst[0] = lo;
    dst[1] = hi;
}

// ---------------- weights fp32 -> bf16 (QSCALE folded into first 256 rows of Wq) ----
__global__ __launch_bounds__(256) void wconv(const float* __restrict__ Wq,
                                             const float* __restrict__ Wp,
                                             ushort* __restrict__ Wqb,
                                             ushort* __restrict__ Wpb) {
    int tid = blockIdx.x * 256 + threadIdx.x;   // 262144
    if (tid < 196608) {
        float s = (tid < 65536) ? QSCALE : 1.0f;
        Wqb[tid] = f2bf(Wq[tid] * s);
    } else {
        int i = tid - 196608;
        Wpb[i] = f2bf(Wp[i]);
    }
}

// -------- rel-pos pair table: Up[head*3375 + idx] = pack(bf(rpb[idx]), bf(rpb[idx-1])) ----
__global__ __launch_bounds__(256) void pair_prep(const float* __restrict__ rpb,
                                                 uint* __restrict__ Up) {
    int tid = blockIdx.x * 256 + threadIdx.x;   // 27000
    if (tid >= 27000) return;
    int head = tid / 3375, idx = tid - head * 3375;
    uint lo = f2bf(rpb[idx * 8 + head]);
    uint hi = f2bf(rpb[(idx > 0 ? idx - 1 : 0) * 8 + head]);
    Up[tid] = lo | (hi << 16);
}

// ---------------- MFMA GEMM: C[32768 x 768] = Xw @ Wqb^T -> Q/K/Vf ----------------
// V stored in K=16 MFMA A-fragment order per (w,head):
//   chunk = (n>>4)*2 + (hd>>4); elem = (((n>>2)&3)*16 + (hd&15))*4 + (n&3)
__global__ __launch_bounds__(256) void gemm_qkv(
    const ushort* __restrict__ A,   // [32768][256] bf16
    const ushort* __restrict__ Bw,  // [768][256] bf16
    const float* __restrict__ bq,
    ushort* __restrict__ Q, ushort* __restrict__ K, ushort* __restrict__ Vf) {
    __shared__ short As[128 * 64];
    __shared__ short Bs[128 * 64];
    const int t = threadIdx.x;
    const int wv = t >> 6, lane = t & 63, quad = lane >> 4, col = lane & 15;
    const int m0 = blockIdx.y * 128, n0 = blockIdx.x * 128;
    const int wm = (wv & 1) * 64, wn = (wv >> 1) * 64;

    floatx4 zf = {0.f, 0.f, 0.f, 0.f};
    floatx4 acc[4][4];
#pragma unroll
    for (int i = 0; i < 4; ++i)
#pragma unroll
        for (int j = 0; j < 4; ++j) acc[i][j] = zf;

    for (int kk = 0; kk < 256; kk += 64) {
        __syncthreads();
#pragma unroll
        for (int i = 0; i < 4; ++i) {
            int s = i * 256 + t;
            int row = s >> 3, qs = s & 7;
            int qg = qs ^ (row & 7);
            gl_lds16(A + (size_t)(m0 + row) * 256 + kk + qg * 8,
                     As + (i * 256 + wv * 64) * 8);
        }
#pragma unroll
        for (int i = 0; i < 4; ++i) {
            int s = i * 256 + t;
            int row = s >> 3, qs = s & 7;
            int qg = qs ^ (row & 7);
            gl_lds16(Bw + (size_t)(n0 + row) * 256 + kk + qg * 8,
                     Bs + (i * 256 + wv * 64) * 8);
        }
        __syncthreads();
#pragma unroll
        for (int h = 0; h < 2; ++h) {
            short8 af[4], bf[4];
#pragma unroll
            for (int mi = 0; mi < 4; ++mi) {
                int row = wm + mi * 16 + col;
                af[mi] = *(const short8*)(As + (row * 8 + ((h * 4 + quad) ^ (row & 7))) * 8);
            }
#pragma unroll
            for (int ni = 0; ni < 4; ++ni) {
                int row = wn + ni * 16 + col;
                bf[ni] = *(const short8*)(Bs + (row * 8 + ((h * 4 + quad) ^ (row & 7))) * 8);
            }
#pragma unroll
            for (int mi = 0; mi < 4; ++mi)
#pragma unroll
                for (int ni = 0; ni < 4; ++ni)
                    acc[mi][ni] = __builtin_amdgcn_mfma_f32_16x16x32_bf16(af[mi], bf[ni], acc[mi][ni], 0, 0, 0);
        }
    }

#pragma unroll
    for (int ni = 0; ni < 4; ++ni) {
        int j = n0 + wn + ni * 16 + col;
        int three = j >> 8, head = (j >> 5) & 7, hd = j & 31;
        float bias = bq[j] * ((j < 256) ? QSCALE : 1.0f);
        if (three == 2) {
            int h = hd >> 4, colv = hd & 15;
#pragma unroll
            for (int mi = 0; mi < 4; ++mi) {
#pragma unroll
                for (int r = 0; r < 4; ++r) {
                    int m = m0 + wm + mi * 16 + quad * 4 + r;
                    int w = m >> 9, n = m & 511;
                    size_t off = ((size_t)((w * 8 + head) * 64 + (n >> 4) * 2 + h) << 8)
                               + ((((n >> 2) & 3) * 16 + colv) << 2) + (n & 3);
                    Vf[off] = f2bf(acc[mi][ni][r] + bias);
                }
            }
        } else {
            ushort* dst = (three == 0) ? Q : K;
#pragma unroll
            for (int mi = 0; mi < 4; ++mi) {
#pragma unroll
                for (int r = 0; r < 4; ++r) {
                    int m = m0 + wm + mi * 16 + quad * 4 + r;
                    int w = m >> 9, n = m & 511;
                    dst[((size_t)(w * 8 + head) * 512 + n) * 32 + hd] = f2bf(acc[mi][ni][r] + bias);
                }
            }
        }
    }
}

// ---------------- MFMA GEMM: out = Y @ Wpb^T + bp, scatter w/ reverse shift ----------
__global__ __launch_bounds__(256) void gemm_proj(
    const ushort* __restrict__ A,   // Y [32768][256] bf16
    const ushort* __restrict__ Bw,  // [256][256] bf16
    const float* __restrict__ bp,
    float* __restrict__ out) {
    __shared__ short As[128 * 64];
    __shared__ short Bs[128 * 64];
    const int t = threadIdx.x;
    const int wv = t >> 6, lane = t & 63, quad = lane >> 4, col = lane & 15;
    const int m0 = blockIdx.y * 128, n0 = blockIdx.x * 128;
    const int wm = (wv & 1) * 64, wn = (wv >> 1) * 64;

    floatx4 zf = {0.f, 0.f, 0.f, 0.f};
    floatx4 acc[4][4];
#pragma unroll
    for (int i = 0; i < 4; ++i)
#pragma unroll
        for (int j = 0; j < 4; ++j) acc[i][j] = zf;

    for (int kk = 0; kk < 256; kk += 64) {
        __syncthreads();
#pragma unroll
        for (int i = 0; i < 4; ++i) {
            int s = i * 256 + t;
            int row = s >> 3, qs = s & 7;
            int qg = qs ^ (row & 7);
            gl_lds16(A + (size_t)(m0 + row) * 256 + kk + qg * 8,
                     As + (i * 256 + wv * 64) * 8);
        }
#pragma unroll
        for (int i = 0; i < 4; ++i) {
            int s = i * 256 + t;
            int row = s >> 3, qs = s & 7;
            int qg = qs ^ (row & 7);
            gl_lds16(Bw + (size_t)(n0 + row) * 256 + kk + qg * 8,
                     Bs + (i * 256 + wv * 64) * 8);
        }
        __syncthreads();
#pragma unroll
        for (int h = 0; h < 2; ++h) {
            short8 af[4], bf[4];
#pragma unroll
            for (int mi = 0; mi < 4; ++mi) {
                int row = wm + mi * 16 + col;
                af[mi] = *(const short8*)(As + (row * 8 + ((h * 4 + quad) ^ (row & 7))) * 8);
            }
#pragma unroll
            for (int ni = 0; ni < 4; ++ni) {
                int row = wn + ni * 16 + col;
                bf[ni] = *(const short8*)(Bs + (row * 8 + ((h * 4 + quad) ^ (row & 7))) * 8);
            }
#pragma unroll
            for (int mi = 0; mi < 4; ++mi)
#pragma unroll
                for (int ni = 0; ni < 4; ++ni)
                    acc[mi][ni] = __builtin_amdgcn_mfma_f32_16x16x32_bf16(af[mi], bf[ni], acc[mi][ni], 0, 0, 0);
        }
    }

#pragma unroll
    for (int ni = 0; ni < 4; ++ni) {
        int j = n0 + wn + ni * 16 + col;
        float bias = bp[j];
#pragma unroll
        for (int mi = 0; mi < 4; ++mi) {
#pragma unroll
            for (int r = 0; r < 4; ++r) {
                int m = m0 + wm + mi * 16 + quad * 4 + r;
                out[spatial_off(m) + j] = acc[mi][ni][r] + bias;
            }
        }
    }
}

// ---------------- MFMA windowed attention: S^T form, 2-chunk keys, no-max softmax ----
__global__ __launch_bounds__(256, 2) void attn_kernel(
    const ushort* __restrict__ Q, const ushort* __restrict__ K,
    const ushort* __restrict__ Vf, const uint* __restrict__ Up,
    ushort* __restrict__ Y) {
    __shared__ short Kl[512 * 32];       // row-major [key][hd] bf16
    __shared__ short Vs[64 * 256];       // K=16 A-fragment order (pre-permuted in global)
    __shared__ uint  Ul[3375];           // per-head rel-pos pair table

    const int t = threadIdx.x;
    const int bid = blockIdx.x;
    const int w = bid >> 3, head = bid & 7;
    const int wh = w >> 4, ww = (w >> 2) & 3, wd = w & 3;
    const int wv = t >> 6, lane = t & 63, quad = lane >> 4, col = lane & 15;

    const ushort* Kg = K + (size_t)(w * 8 + head) * 512 * 32;
    const ushort* Vg = Vf + (size_t)(w * 8 + head) * 512 * 32;
    const ushort* Qg = Q + (size_t)(w * 8 + head) * 512 * 32;

    // ---- stage K and V once (async direct-to-LDS, linear) ----
#pragma unroll
    for (int i = 0; i < 8; ++i) {
        gl_lds16(Kg + (size_t)(i * 256 + t) * 8, Kl + (i * 256 + wv * 64) * 8);
        gl_lds16(Vg + (size_t)(i * 256 + t) * 8, Vs + (i * 256 + wv * 64) * 8);
    }
    // ---- stage this head's pair table ----
    const uint* Uph = Up + head * 3375;
    for (int i = t; i < 3375; i += 256) Ul[i] = Uph[i];
    __syncthreads();

    const bool boundary = (wh == 3) | (ww == 3) | (wd == 3);
    floatx4 zf = {0.f, 0.f, 0.f, 0.f};

    for (int qs = 0; qs < 8; ++qs) {
        const int qt = wv * 8 + qs;
        const short8 qf = *(const short8*)(Qg + (size_t)(qt * 16 + col) * 32 + quad * 8);

        const int qrow = qt * 16 + col;
        const int qh = qrow >> 6, qw = (qrow >> 3) & 7, qd = qrow & 7;
        const int Base0 = ((qh + 7) * 15 + (qw + 7 - (quad >> 1))) * 15
                        + (qd - ((quad & 1) << 2) + 7);
        const int cq = ((wh == 3) ? (1 + ((qrow >> 8) & 1)) * 16 : 0)
                     + ((ww == 3) ? (1 + ((qrow >> 5) & 1)) * 4 : 0)
                     + ((wd == 3) ? (1 + ((qrow >> 2) & 1)) : 0);

        float rs = 0.f;
        floatx4 o0 = zf, o1 = zf;

        // ---- keys in 2 chunks of 256: acc[16] produced & consumed per chunk ----
        for (int c = 0; c < 2; ++c) {   // rolled: keeps register liveness low
            const short* KlC = Kl + c * 8192;
            const short* VsC = Vs + c * 8192;
            const int BaseC = Base0 - c * 900;
            const int ckh = (wh == 3) ? ((1 + c) * 16) : 0;

            floatx4 acc[16];
#pragma unroll
            for (int tt = 0; tt < 16; ++tt) {
                short8 kf = *(const short8*)(KlC + tt * 512 + col * 32 + quad * 8);
                acc[tt] = __builtin_amdgcn_mfma_f32_16x16x32_bf16(kf, qf, zf, 0, 0, 0);
            }

#pragma unroll
            for (int tt = 0; tt < 16; ++tt) {
                const int Kt2 = ((tt >> 2) * 15 + (tt & 3) * 2) * 15;
                uint p0 = Ul[BaseC - Kt2];
                uint p1 = Ul[BaseC - Kt2 - 2];
                float s0 = acc[tt][0] + __uint_as_float(p0 << 16);
                float s1 = acc[tt][1] + __uint_as_float(p0 & 0xffff0000u);
                float s2 = acc[tt][2] + __uint_as_float(p1 << 16);
                float s3 = acc[tt][3] + __uint_as_float(p1 & 0xffff0000u);
                if (boundary) {
                    int ck = ckh
                           + ((ww == 3) ? (1 + ((tt >> 1) & 1)) * 4 : 0)
                           + ((wd == 3) ? (1 + (quad & 1)) : 0);
                    float madd = (cq == ck) ? 0.f : -100.f;
                    s0 += madd; s1 += madd; s2 += madd; s3 += madd;
                }
                // softmax without max-subtraction: scores are O(1), fp32-safe;
                // masked entries exp2(-144) flush to 0
                float e0 = exp2f(s0 * 1.442695041f);
                float e1 = exp2f(s1 * 1.442695041f);
                float e2 = exp2f(s2 * 1.442695041f);
                float e3 = exp2f(s3 * 1.442695041f);
                rs += (e0 + e1) + (e2 + e3);
                uint2v pp;
                pp[0] = (uint)f2bf(e0) | ((uint)f2bf(e1) << 16);
                pp[1] = (uint)f2bf(e2) | ((uint)f2bf(e3) << 16);
                s4v pf = __builtin_bit_cast(s4v, pp);
                s4v v0 = *(const s4v*)(VsC + ((tt * 2 + 0) << 8) + lane * 4);
                s4v v1 = *(const s4v*)(VsC + ((tt * 2 + 1) << 8) + lane * 4);
                o0 = __builtin_amdgcn_mfma_f32_16x16x16bf16_1k(v0, pf, o0, 0, 0, 0);
                o1 = __builtin_amdgcn_mfma_f32_16x16x16bf16_1k(v1, pf, o1, 0, 0, 0);
            }
        }

        rs += __shfl_xor(rs, 16);
        rs += __shfl_xor(rs, 32);
        const float inv = 1.0f / rs;

        // ---- epilogue: O^T row=hd(quad*4+r), col=q(lane&15); two packed 8B stores ----
        int token = w * 512 + qt * 16 + col;
        ushort* Yb = Y + (size_t)token * 256 + head * 32 + quad * 4;
        uint2v y0, y1;
        y0[0] = (uint)f2bf(o0[0] * inv) | ((uint)f2bf(o0[1] * inv) << 16);
        y0[1] = (uint)f2bf(o0[2] * inv) | ((uint)f2bf(o0[3] * inv) << 16);
        y1[0] = (uint)f2bf(o1[0] * inv) | ((uint)f2bf(o1[1] * inv) << 16);
        y1[1] = (uint)f2bf(o1[2] * inv) | ((uint)f2bf(o1[3] * inv) << 16);
        *(uint2v*)(Yb) = y0;
        *(uint2v*)(Yb + 16) = y1;
    }
}

extern "C" void kernel_launch(void* const* d_in, const int* in_sizes, int n_in,
                              void* d_out, int out_size, void* d_ws, size_t ws_size,
                              hipStream_t stream) {
    const float* x      = (const float*)d_in[0];
    const float* qkv_w  = (const float*)d_in[1];
    const float* qkv_b  = (const float*)d_in[2];
    const float* proj_w = (const float*)d_in[3];
    const float* proj_b = (const float*)d_in[4];
    const float* rpb    = (const float*)d_in[5];
    float* out = (float*)d_out;

    // ws layout (ushorts): Xw 8.39M | Q 8.39M | K 8.39M | Vf 8.39M | Y 8.39M | Up 54K | Wqb | Wpb
    ushort* Xw  = (ushort*)d_ws;
    ushort* Q   = Xw + 8388608;
    ushort* K   = Q + 8388608;
    ushort* Vf  = K + 8388608;
    ushort* Y   = Vf + 8388608;
    uint*   Up  = (uint*)(Y + 8388608);
    ushort* Wqb = (ushort*)(Up + 27008);
    ushort* Wpb = Wqb + 196608;

    xconv<<<dim3(4096), dim3(256), 0, stream>>>(x, Xw);
    wconv<<<dim3(1024), dim3(256), 0, stream>>>(qkv_w, proj_w, Wqb, Wpb);
    pair_prep<<<dim3(106), dim3(256), 0, stream>>>(rpb, Up);
    gemm_qkv<<<dim3(6, 256), dim3(256), 0, stream>>>(Xw, Wqb, qkv_b, Q, K, Vf);
    attn_kernel<<<dim3(512), dim3(256), 0, stream>>>(Q, K, Vf, Up, Y);
    gemm_proj<<<dim3(2, 256), dim3(256), 0, stream>>>(Y, Wpb, proj_b, out);
}

// Round 9
// 200.887 us; speedup vs baseline: 2.1545x; 1.0440x over previous
//
#include <hip/hip_runtime.h>

typedef __attribute__((ext_vector_type(8))) short short8;
typedef __attribute__((ext_vector_type(4))) short s4v;
typedef __attribute__((ext_vector_type(2))) uint uint2v;
typedef __attribute__((ext_vector_type(4))) float floatx4;

#define CCH   256
#define QSCALE 0.17677669529663687f  // 32^-0.5
#define LOG2E  1.4426950408889634f

__device__ __forceinline__ unsigned short f2bf(float f) {
    unsigned u = __float_as_uint(f);
    u = u + 0x7fffu + ((u >> 16) & 1u);
    return (unsigned short)(u >> 16);
}

// pack two fp32 -> bf16x2 with round-half-up: (u+0x8000)>>16, fused via v_perm
__device__ __forceinline__ uint pk2bf(float a, float b) {
    uint ua = __float_as_uint(a) + 0x8000u;
    uint ub = __float_as_uint(b) + 0x8000u;
    return __builtin_amdgcn_perm(ub, ua, 0x07060302u);
}

__device__ __forceinline__ void gl_lds16(const void* g, void* l) {
    __builtin_amdgcn_global_load_lds((const __attribute__((address_space(1))) void*)g,
                                     (__attribute__((address_space(3))) void*)l, 16, 0, 0);
}

// token (w*512+n) -> flat spatial offset (*CCH) in x/out with +4 cyclic shift
__device__ __forceinline__ int spatial_off(int token) {
    int w = token >> 9, n = token & 511;
    int wh = w >> 4, ww = (w >> 2) & 3, wd = w & 3;
    int h1 = n >> 6, w1 = (n >> 3) & 7, d1 = n & 7;
    int gh = (wh * 8 + h1 + 4) & 31;
    int gw = (ww * 8 + w1 + 4) & 31;
    int gd = (wd * 8 + d1 + 4) & 31;
    return ((gh * 32 + gw) * 32 + gd) * CCH;
}

// ---------------- x (fp32, spatial) -> Xw (bf16, window-token order) ----------------
__global__ __launch_bounds__(256) void xconv(const float* __restrict__ x,
                                             ushort* __restrict__ Xw) {
    int tid = blockIdx.x * 256 + threadIdx.x;   // 1048576
    int token = tid >> 5, c8 = (tid & 31) * 8;
    const float* src = x + spatial_off(token) + c8;
    float4 a = *(const float4*)src;
    float4 b = *(const float4*)(src + 4);
    uint2v lo, hi;
    lo[0] = pk2bf(a.x, a.y);
    lo[1] = pk2bf(a.z, a.w);
    hi[0] = pk2bf(b.x, b.y);
    hi[1] = pk2bf(b.z, b.w);
    uint2v* dst = (uint2v*)(Xw + (size_t)token * 256 + c8);
    dst[0] = lo;
    dst[1] = hi;
}

// ---- weights fp32 -> bf16 (QSCALE*LOG2E folded into first 256 rows of Wq) ----
__global__ __launch_bounds__(256) void wconv(const float* __restrict__ Wq,
                                             const float* __restrict__ Wp,
                                             ushort* __restrict__ Wqb,
                                             ushort* __restrict__ Wpb) {
    int tid = blockIdx.x * 256 + threadIdx.x;   // 262144
    if (tid < 196608) {
        float s = (tid < 65536) ? (QSCALE * LOG2E) : 1.0f;
        Wqb[tid] = f2bf(Wq[tid] * s);
    } else {
        int i = tid - 196608;
        Wpb[i] = f2bf(Wp[i]);
    }
}

// -------- rel-pos pair table (pre-scaled by LOG2E):
// Up[head*3375 + idx] = pack(bf(rpb[idx]*log2e), bf(rpb[idx-1]*log2e)) ----
__global__ __launch_bounds__(256) void pair_prep(const float* __restrict__ rpb,
                                                 uint* __restrict__ Up) {
    int tid = blockIdx.x * 256 + threadIdx.x;   // 27000
    if (tid >= 27000) return;
    int head = tid / 3375, idx = tid - head * 3375;
    uint lo = f2bf(rpb[idx * 8 + head] * LOG2E);
    uint hi = f2bf(rpb[(idx > 0 ? idx - 1 : 0) * 8 + head] * LOG2E);
    Up[tid] = lo | (hi << 16);
}

// ---------------- MFMA GEMM: C[32768 x 768] = Xw @ Wqb^T -> Q/K/Vf ----------------
// V stored in K=16 MFMA A-fragment order per (w,head):
//   chunk = (n>>4)*2 + (hd>>4); elem = (((n>>2)&3)*16 + (hd&15))*4 + (n&3)
__global__ __launch_bounds__(256) void gemm_qkv(
    const ushort* __restrict__ A,   // [32768][256] bf16
    const ushort* __restrict__ Bw,  // [768][256] bf16
    const float* __restrict__ bq,
    ushort* __restrict__ Q, ushort* __restrict__ K, ushort* __restrict__ Vf) {
    __shared__ short As[128 * 64];
    __shared__ short Bs[128 * 64];
    const int t = threadIdx.x;
    const int wv = t >> 6, lane = t & 63, quad = lane >> 4, col = lane & 15;
    const int m0 = blockIdx.y * 128, n0 = blockIdx.x * 128;
    const int wm = (wv & 1) * 64, wn = (wv >> 1) * 64;

    floatx4 zf = {0.f, 0.f, 0.f, 0.f};
    floatx4 acc[4][4];
#pragma unroll
    for (int i = 0; i < 4; ++i)
#pragma unroll
        for (int j = 0; j < 4; ++j) acc[i][j] = zf;

    for (int kk = 0; kk < 256; kk += 64) {
        __syncthreads();
#pragma unroll
        for (int i = 0; i < 4; ++i) {
            int s = i * 256 + t;
            int row = s >> 3, qs = s & 7;
            int qg = qs ^ (row & 7);
            gl_lds16(A + (size_t)(m0 + row) * 256 + kk + qg * 8,
                     As + (i * 256 + wv * 64) * 8);
        }
#pragma unroll
        for (int i = 0; i < 4; ++i) {
            int s = i * 256 + t;
            int row = s >> 3, qs = s & 7;
            int qg = qs ^ (row & 7);
            gl_lds16(Bw + (size_t)(n0 + row) * 256 + kk + qg * 8,
                     Bs + (i * 256 + wv * 64) * 8);
        }
        __syncthreads();
#pragma unroll
        for (int h = 0; h < 2; ++h) {
            short8 af[4], bf[4];
#pragma unroll
            for (int mi = 0; mi < 4; ++mi) {
                int row = wm + mi * 16 + col;
                af[mi] = *(const short8*)(As + (row * 8 + ((h * 4 + quad) ^ (row & 7))) * 8);
            }
#pragma unroll
            for (int ni = 0; ni < 4; ++ni) {
                int row = wn + ni * 16 + col;
                bf[ni] = *(const short8*)(Bs + (row * 8 + ((h * 4 + quad) ^ (row & 7))) * 8);
            }
#pragma unroll
            for (int mi = 0; mi < 4; ++mi)
#pragma unroll
                for (int ni = 0; ni < 4; ++ni)
                    acc[mi][ni] = __builtin_amdgcn_mfma_f32_16x16x32_bf16(af[mi], bf[ni], acc[mi][ni], 0, 0, 0);
        }
    }

#pragma unroll
    for (int ni = 0; ni < 4; ++ni) {
        int j = n0 + wn + ni * 16 + col;
        int three = j >> 8, head = (j >> 5) & 7, hd = j & 31;
        float bias = bq[j] * ((j < 256) ? (QSCALE * LOG2E) : 1.0f);
        if (three == 2) {
            int h = hd >> 4, colv = hd & 15;
#pragma unroll
            for (int mi = 0; mi < 4; ++mi) {
                int mb = m0 + wm + mi * 16 + quad * 4;   // n&3 = r, contiguous
                int w = mb >> 9, n = mb & 511;
                size_t off = ((size_t)((w * 8 + head) * 64 + (n >> 4) * 2 + h) << 8)
                           + ((((n >> 2) & 3) * 16 + colv) << 2);
                uint2v pv;
                pv[0] = pk2bf(acc[mi][ni][0] + bias, acc[mi][ni][1] + bias);
                pv[1] = pk2bf(acc[mi][ni][2] + bias, acc[mi][ni][3] + bias);
                *(uint2v*)(Vf + off) = pv;
            }
        } else {
            ushort* dst = (three == 0) ? Q : K;
#pragma unroll
            for (int mi = 0; mi < 4; ++mi) {
#pragma unroll
                for (int r = 0; r < 4; ++r) {
                    int m = m0 + wm + mi * 16 + quad * 4 + r;
                    int w = m >> 9, n = m & 511;
                    dst[((size_t)(w * 8 + head) * 512 + n) * 32 + hd] = f2bf(acc[mi][ni][r] + bias);
                }
            }
        }
    }
}

// ---------------- MFMA GEMM: out = Y @ Wpb^T + bp, scatter w/ reverse shift ----------
__global__ __launch_bounds__(256) void gemm_proj(
    const ushort* __restrict__ A,   // Y [32768][256] bf16
    const ushort* __restrict__ Bw,  // [256][256] bf16
    const float* __restrict__ bp,
    float* __restrict__ out) {
    __shared__ short As[128 * 64];
    __shared__ short Bs[128 * 64];
    const int t = threadIdx.x;
    const int wv = t >> 6, lane = t & 63, quad = lane >> 4, col = lane & 15;
    const int m0 = blockIdx.y * 128, n0 = blockIdx.x * 128;
    const int wm = (wv & 1) * 64, wn = (wv >> 1) * 64;

    floatx4 zf = {0.f, 0.f, 0.f, 0.f};
    floatx4 acc[4][4];
#pragma unroll
    for (int i = 0; i < 4; ++i)
#pragma unroll
        for (int j = 0; j < 4; ++j) acc[i][j] = zf;

    for (int kk = 0; kk < 256; kk += 64) {
        __syncthreads();
#pragma unroll
        for (int i = 0; i < 4; ++i) {
            int s = i * 256 + t;
            int row = s >> 3, qs = s & 7;
            int qg = qs ^ (row & 7);
            gl_lds16(A + (size_t)(m0 + row) * 256 + kk + qg * 8,
                     As + (i * 256 + wv * 64) * 8);
        }
#pragma unroll
        for (int i = 0; i < 4; ++i) {
            int s = i * 256 + t;
            int row = s >> 3, qs = s & 7;
            int qg = qs ^ (row & 7);
            gl_lds16(Bw + (size_t)(n0 + row) * 256 + kk + qg * 8,
                     Bs + (i * 256 + wv * 64) * 8);
        }
        __syncthreads();
#pragma unroll
        for (int h = 0; h < 2; ++h) {
            short8 af[4], bf[4];
#pragma unroll
            for (int mi = 0; mi < 4; ++mi) {
                int row = wm + mi * 16 + col;
                af[mi] = *(const short8*)(As + (row * 8 + ((h * 4 + quad) ^ (row & 7))) * 8);
            }
#pragma unroll
            for (int ni = 0; ni < 4; ++ni) {
                int row = wn + ni * 16 + col;
                bf[ni] = *(const short8*)(Bs + (row * 8 + ((h * 4 + quad) ^ (row & 7))) * 8);
            }
#pragma unroll
            for (int mi = 0; mi < 4; ++mi)
#pragma unroll
                for (int ni = 0; ni < 4; ++ni)
                    acc[mi][ni] = __builtin_amdgcn_mfma_f32_16x16x32_bf16(af[mi], bf[ni], acc[mi][ni], 0, 0, 0);
        }
    }

#pragma unroll
    for (int ni = 0; ni < 4; ++ni) {
        int j = n0 + wn + ni * 16 + col;
        float bias = bp[j];
#pragma unroll
        for (int mi = 0; mi < 4; ++mi) {
#pragma unroll
            for (int r = 0; r < 4; ++r) {
                int m = m0 + wm + mi * 16 + quad * 4 + r;
                out[spatial_off(m) + j] = acc[mi][ni][r] + bias;
            }
        }
    }
}

// ---------------- MFMA windowed attention: S^T form, bias in MFMA C, log2-domain ----
__global__ __launch_bounds__(256, 2) void attn_kernel(
    const ushort* __restrict__ Q, const ushort* __restrict__ K,
    const ushort* __restrict__ Vf, const uint* __restrict__ Up,
    ushort* __restrict__ Y) {
    __shared__ short Kl[512 * 32];       // row-major [key][hd] bf16
    __shared__ short Vs[64 * 256];       // K=16 A-fragment order (pre-permuted in global)
    __shared__ uint  Ul[3375];           // per-head rel-pos pair table (log2-scaled)

    const int t = threadIdx.x;
    const int bid = blockIdx.x;
    const int w = bid >> 3, head = bid & 7;
    const int wh = w >> 4, ww = (w >> 2) & 3, wd = w & 3;
    const int wv = t >> 6, lane = t & 63, quad = lane >> 4, col = lane & 15;

    const ushort* Kg = K + (size_t)(w * 8 + head) * 512 * 32;
    const ushort* Vg = Vf + (size_t)(w * 8 + head) * 512 * 32;
    const ushort* Qg = Q + (size_t)(w * 8 + head) * 512 * 32;

    // ---- stage K and V once (async direct-to-LDS, linear) ----
#pragma unroll
    for (int i = 0; i < 8; ++i) {
        gl_lds16(Kg + (size_t)(i * 256 + t) * 8, Kl + (i * 256 + wv * 64) * 8);
        gl_lds16(Vg + (size_t)(i * 256 + t) * 8, Vs + (i * 256 + wv * 64) * 8);
    }
    // ---- stage this head's pair table ----
    const uint* Uph = Up + head * 3375;
    for (int i = t; i < 3375; i += 256) Ul[i] = Uph[i];
    __syncthreads();

    const bool boundary = (wh == 3) | (ww == 3) | (wd == 3);
    floatx4 zf = {0.f, 0.f, 0.f, 0.f};

    for (int qs = 0; qs < 8; ++qs) {
        const int qt = wv * 8 + qs;
        const short8 qf = *(const short8*)(Qg + (size_t)(qt * 16 + col) * 32 + quad * 8);

        const int qrow = qt * 16 + col;
        const int qh = qrow >> 6, qw = (qrow >> 3) & 7, qd = qrow & 7;
        const int Base0 = ((qh + 7) * 15 + (qw + 7 - (quad >> 1))) * 15
                        + (qd - ((quad & 1) << 2) + 7);
        const int cq = ((wh == 3) ? (1 + ((qrow >> 8) & 1)) * 16 : 0)
                     + ((ww == 3) ? (1 + ((qrow >> 5) & 1)) * 4 : 0)
                     + ((wd == 3) ? (1 + ((qrow >> 2) & 1)) : 0);

        float rs = 0.f;
        floatx4 o0 = zf, o1 = zf;

        // ---- keys in 2 chunks of 256: acc[16] produced & consumed per chunk ----
        for (int c = 0; c < 2; ++c) {   // rolled: keeps register liveness low
            const short* KlC = Kl + c * 8192;
            const short* VsC = Vs + c * 8192;
            const int BaseC = Base0 - c * 900;
            const int ckh = (wh == 3) ? ((1 + c) * 16) : 0;

            floatx4 acc[16];
            // produce: S^T tiles with bias (and mask) preloaded into the C operand
#pragma unroll
            for (int tt = 0; tt < 16; ++tt) {
                const int Kt2 = ((tt >> 2) * 15 + (tt & 3) * 2) * 15;
                uint p0 = Ul[BaseC - Kt2];
                uint p1 = Ul[BaseC - Kt2 - 2];
                floatx4 cf;
                cf[0] = __uint_as_float(p0 << 16);
                cf[1] = __uint_as_float(p0 & 0xffff0000u);
                cf[2] = __uint_as_float(p1 << 16);
                cf[3] = __uint_as_float(p1 & 0xffff0000u);
                if (boundary) {
                    int ck = ckh
                           + ((ww == 3) ? (1 + ((tt >> 1) & 1)) * 4 : 0)
                           + ((wd == 3) ? (1 + (quad & 1)) : 0);
                    float madd = (cq == ck) ? 0.f : -144.269504f;  // -100*log2e
                    cf[0] += madd; cf[1] += madd; cf[2] += madd; cf[3] += madd;
                }
                short8 kf = *(const short8*)(KlC + tt * 512 + col * 32 + quad * 8);
                acc[tt] = __builtin_amdgcn_mfma_f32_16x16x32_bf16(kf, qf, cf, 0, 0, 0);
            }

            // consume: exp2 (scores already in log2 domain), pack, PV
#pragma unroll
            for (int tt = 0; tt < 16; ++tt) {
                float e0 = exp2f(acc[tt][0]);
                float e1 = exp2f(acc[tt][1]);
                float e2 = exp2f(acc[tt][2]);
                float e3 = exp2f(acc[tt][3]);
                rs += (e0 + e1) + (e2 + e3);
                uint2v pp;
                pp[0] = pk2bf(e0, e1);
                pp[1] = pk2bf(e2, e3);
                s4v pf = __builtin_bit_cast(s4v, pp);
                s4v v0 = *(const s4v*)(VsC + ((tt * 2 + 0) << 8) + lane * 4);
                s4v v1 = *(const s4v*)(VsC + ((tt * 2 + 1) << 8) + lane * 4);
                o0 = __builtin_amdgcn_mfma_f32_16x16x16bf16_1k(v0, pf, o0, 0, 0, 0);
                o1 = __builtin_amdgcn_mfma_f32_16x16x16bf16_1k(v1, pf, o1, 0, 0, 0);
            }
        }

        rs += __shfl_xor(rs, 16);
        rs += __shfl_xor(rs, 32);
        const float inv = __builtin_amdgcn_rcpf(rs);

        // ---- epilogue: O^T row=hd(quad*4+r), col=q(lane&15); two packed 8B stores ----
        int token = w * 512 + qt * 16 + col;
        ushort* Yb = Y + (size_t)token * 256 + head * 32 + quad * 4;
        uint2v y0, y1;
        y0[0] = pk2bf(o0[0] * inv, o0[1] * inv);
        y0[1] = pk2bf(o0[2] * inv, o0[3] * inv);
        y1[0] = pk2bf(o1[0] * inv, o1[1] * inv);
        y1[1] = pk2bf(o1[2] * inv, o1[3] * inv);
        *(uint2v*)(Yb) = y0;
        *(uint2v*)(Yb + 16) = y1;
    }
}

extern "C" void kernel_launch(void* const* d_in, const int* in_sizes, int n_in,
                              void* d_out, int out_size, void* d_ws, size_t ws_size,
                              hipStream_t stream) {
    const float* x      = (const float*)d_in[0];
    const float* qkv_w  = (const float*)d_in[1];
    const float* qkv_b  = (const float*)d_in[2];
    const float* proj_w = (const float*)d_in[3];
    const float* proj_b = (const float*)d_in[4];
    const float* rpb    = (const float*)d_in[5];
    float* out = (float*)d_out;

    // ws layout (ushorts): Xw 8.39M | Q 8.39M | K 8.39M | Vf 8.39M | Y 8.39M | Up 54K | Wqb | Wpb
    ushort* Xw  = (ushort*)d_ws;
    ushort* Q   = Xw + 8388608;
    ushort* K   = Q + 8388608;
    ushort* Vf  = K + 8388608;
    ushort* Y   = Vf + 8388608;
    uint*   Up  = (uint*)(Y + 8388608);
    ushort* Wqb = (ushort*)(Up + 27008);
    ushort* Wpb = Wqb + 196608;

    xconv<<<dim3(4096), dim3(256), 0, stream>>>(x, Xw);
    wconv<<<dim3(1024), dim3(256), 0, stream>>>(qkv_w, proj_w, Wqb, Wpb);
    pair_prep<<<dim3(106), dim3(256), 0, stream>>>(rpb, Up);
    gemm_qkv<<<dim3(6, 256), dim3(256), 0, stream>>>(Xw, Wqb, qkv_b, Q, K, Vf);
    attn_kernel<<<dim3(512), dim3(256), 0, stream>>>(Q, K, Vf, Up, Y);
    gemm_proj<<<dim3(2, 256), dim3(256), 0, stream>>>(Y, Wpb, proj_b, out);
}